// Round 8
// baseline (2937.462 us; speedup 1.0000x reference)
//
#include <hip/hip_runtime.h>

typedef unsigned int uint;
typedef unsigned short ushort;
typedef unsigned long long u64;
typedef __attribute__((ext_vector_type(8))) short bf16x8;
typedef __attribute__((ext_vector_type(4))) float f32x4;

// Problem constants
#define T_STEPS 512
#define BATCH   512
#define NB      8       // batch rows per replica
#define RD      16      // inter-stage ring depth (power of 2)
#define XS      168     // xh plane row stride (ushort)
#define CSTR    12      // c-ring pad: floats per (slot,sidx) row
#define OUTC    96
#define FSTR    32      // flag stride in uints (128B line per flag)

__device__ __forceinline__ ushort f2bf(float f){
  uint u = __builtin_bit_cast(uint, f);
  u = (u + 0x7FFFu + ((u >> 16) & 1u)) >> 16;   // RNE
  return (ushort)u;
}
__device__ __forceinline__ float bf2f(ushort h){
  uint u = ((uint)h) << 16; return __builtin_bit_cast(float, u);
}
__device__ __forceinline__ float sigm(float x){
  float e = __builtin_exp2f(-1.44269504f * x);
  return __builtin_amdgcn_rcpf(1.0f + e);
}
__device__ __forceinline__ float tanh_fast(float x){
  float e = __builtin_exp2f(-2.88539008f * x);
  return 2.0f * __builtin_amdgcn_rcpf(1.0f + e) - 1.0f;
}
// Relaxed agent-scope atomics: LLC-coherent, no L1/L2 invalidate/writeback.
__device__ __forceinline__ uint aload32(const uint* p){
  return __hip_atomic_load(p, __ATOMIC_RELAXED, __HIP_MEMORY_SCOPE_AGENT);
}
__device__ __forceinline__ void astore32(uint* p, uint v){
  __hip_atomic_store(p, v, __ATOMIC_RELAXED, __HIP_MEMORY_SCOPE_AGENT);
}
__device__ __forceinline__ u64 aload64(const u64* p){
  return __hip_atomic_load(p, __ATOMIC_RELAXED, __HIP_MEMORY_SCOPE_AGENT);
}
__device__ __forceinline__ void astore64(u64* p, u64 v){
  __hip_atomic_store(p, v, __ATOMIC_RELAXED, __HIP_MEMORY_SCOPE_AGENT);
}

// 4-stage pipeline (stage = blockIdx.x>>6, rep = blockIdx.x&63), NB=8 rows.
// 256 threads = 4 waves = 1 wave/SIMD -> 512 unified VGPRs/wave so ALL weight
// fragments (320 regs) + proj (24) stay register-resident (the 512-thread
// variants capped at 256 regs/wave and re-materialized weights every step).
// Each wave owns 32 states as two 16-column MFMA groups.
__global__ __launch_bounds__(256, 1)
void rnn_pipeline(const float* __restrict__ x,
                  const float* __restrict__ W0, const float* __restrict__ b0,
                  const float* __restrict__ W1, const float* __restrict__ b1,
                  const float* __restrict__ W2, const float* __restrict__ b2,
                  const float* __restrict__ W3, const float* __restrict__ b3,
                  const float* __restrict__ Wa, const float* __restrict__ ba,
                  float* __restrict__ y_out,
                  uint* __restrict__ prod, uint* __restrict__ consA,
                  uint* __restrict__ consB,
                  u64* __restrict__ hop0, u64* __restrict__ hop1,
                  u64* __restrict__ hop2)
{
  const int tid  = threadIdx.x;
  const int wv   = tid >> 6;      // wave 0..3
  const int lane = tid & 63;
  const int l15  = lane & 15;
  const int hi   = lane >> 4;     // 0..3
  const int rep  = blockIdx.x & 63;
  const int stage= blockIdx.x >> 6;
  const int b0r  = rep * NB;

  const int dil = (stage==0)?1:(stage==1)?3:(stage==2)?6:12;
  const int KIN = (stage==0)?64:96;
  const int K   = KIN + 64;
  const float* Wl = (stage==0)?W0:(stage==1)?W1:(stage==2)?W2:W3;
  const float* bl = (stage==0)?b0:(stage==1)?b1:(stage==2)?b2:b3;

  __shared__ __align__(16) ushort xh_hi[16*XS], xh_lo[16*XS];  // A-operand planes
  __shared__ __align__(16) float  sh_c[12*128*CSTR];           // c ring [slot][sidx][12]
  __shared__ __align__(16) ushort h_hi[12*NB*32], h_lo[12*NB*32]; // h ring planes
  __shared__ __align__(16) ushort outp[2304];  // [hi 768][lo 768] (+proj overread pad)
  __shared__ __align__(16) ushort o1p[1536];   // stage3: out1 planes
  __shared__ __align__(16) float  o3f[NB*OUTC];// stage3: out3 fp32
  __shared__ __align__(16) float  yst[512];    // stage3: deferred y (step t-1)

  for (int i = tid; i < 16*XS; i += 256){ xh_hi[i] = 0; xh_lo[i] = 0; }
  for (int i = tid; i < 12*128*CSTR; i += 256) sh_c[i] = 0.0f;
  for (int i = tid; i < 12*NB*32; i += 256){ h_hi[i] = 0; h_lo[i] = 0; }
  for (int i = tid; i < 2304; i += 256) outp[i] = 0;
  for (int i = tid; i < 1536; i += 256) o1p[i] = 0;
  for (int i = tid; i < NB*OUTC; i += 256) o3f[i] = 0.0f;
  yst[tid] = 0.0f; yst[tid + 256] = 0.0f;

  const int sidx = 32*wv + l15;  // group g owns state sidx + 16*g

  // Layer weights as split-bf16 MFMA B-fragments, 2 state-groups per wave.
  bf16x8 whi[2][4][5], wlo[2][4][5];
  #pragma unroll
  for (int g = 0; g < 2; ++g){
    #pragma unroll
    for (int j = 0; j < 4; ++j){
      const int grow = 128*j + sidx + 16*g;
      #pragma unroll
      for (int ks = 0; ks < 5; ++ks){
        bf16x8 vh, vl;
        const int cb = ks*32 + hi*8;
        if (cb < K){
          const float* p = Wl + (size_t)grow*K + cb;
          #pragma unroll
          for (int i = 0; i < 8; ++i){
            float w = p[i];
            ushort h = f2bf(w);
            vh[i] = (short)h;
            vl[i] = (short)f2bf(w - bf2f(h));
          }
        } else {
          #pragma unroll
          for (int i = 0; i < 8; ++i){ vh[i] = 0; vl[i] = 0; }
        }
        whi[g][j][ks] = vh; wlo[g][j][ks] = vl;
      }
    }
  }
  float bias[2][4];
  #pragma unroll
  for (int g = 0; g < 2; ++g)
    #pragma unroll
    for (int j = 0; j < 4; ++j) bias[g][j] = bl[128*j + sidx + 16*g];

  // Projection weights (stage3): ocol = 16*wv + l15 covers 0..63 with 4 waves
  bf16x8 phi[3], plo[3];
  #pragma unroll
  for (int ks = 0; ks < 3; ++ks){
    bf16x8 z;
    #pragma unroll
    for (int i = 0; i < 8; ++i) z[i]=0;
    phi[ks]=z; plo[ks]=z;
  }
  float bav = 0.0f;
  if (stage == 3){
    const int ocol = 16*wv + l15;
    #pragma unroll
    for (int ks = 0; ks < 3; ++ks){
      const float* p = Wa + (size_t)ocol*96 + ks*32 + hi*8;
      bf16x8 vh, vl;
      #pragma unroll
      for (int i = 0; i < 8; ++i){
        float w = p[i];
        ushort h = f2bf(w);
        vh[i] = (short)h;
        vl[i] = (short)f2bf(w - bf2f(h));
      }
      phi[ks] = vh; plo[ks] = vl;
    }
    bav = ba[ocol];
  }

  // Flag wiring (each flag on its own 128B line)
  uint* up_prod  = (stage==1)? &prod[rep*FSTR] : (stage==2)? &prod[(64+rep)*FSTR] :
                   (stage==3)? &prod[(128+rep)*FSTR] : nullptr;
  uint* up_prod1 = (stage==3)? &prod[(64+rep)*FSTR] : nullptr;
  uint* my_prod  = (stage==0)? &prod[rep*FSTR] : (stage==1)? &prod[(64+rep)*FSTR] :
                   (stage==2)? &prod[(128+rep)*FSTR] : nullptr;
  uint* my_consA = (stage==1)? &consA[rep*FSTR] : (stage==2)? &consA[(64+rep)*FSTR] :
                   (stage==3)? &consA[(128+rep)*FSTR] : nullptr;
  uint* my_consB = (stage==3)? &consB[rep*FSTR] : nullptr;
  uint* dnA      = (stage==0)? &consA[rep*FSTR] : (stage==1)? &consA[(64+rep)*FSTR] :
                   (stage==2)? &consA[(128+rep)*FSTR] : nullptr;
  uint* dnB      = (stage==1)? &consB[rep*FSTR] : nullptr;
  const u64* hop_in  = (stage==1)? hop0 : (stage==2)? hop1 : nullptr;
  u64*       hop_out = (stage==0)? hop0 : (stage==1)? hop1 : (stage==2)? hop2 : nullptr;

  __syncthreads();

  // ---- preloop: blocking acquire of step-0 data + initial flag samples ----
  u64 pfA = 0, pfB = 0, pfC = 0, pfD = 0;
  float xv0 = 0.0f, xv1 = 0.0f;
  uint fvU = 0, fvU1 = 0, fvDA = 0, fvDB = 0;
  if (stage == 0){
    xv0 = x[(size_t)(b0r + (tid>>6))*64 + (tid&63)];
    xv1 = x[(size_t)(b0r + (tid>>6) + 4)*64 + (tid&63)];
  } else if (stage < 3){
    do { fvU = aload32(up_prod); if (fvU < 1u) __builtin_amdgcn_s_sleep(2); } while (fvU < 1u);
    pfA = aload64(hop_in + tid);
    if (tid < 128) pfB = aload64(hop_in + 256 + tid);
  } else {
    do { fvU  = aload32(up_prod);  if (fvU  < 1u) __builtin_amdgcn_s_sleep(2); } while (fvU  < 1u);
    do { fvU1 = aload32(up_prod1); if (fvU1 < 1u) __builtin_amdgcn_s_sleep(2); } while (fvU1 < 1u);
    pfA = aload64(hop2 + tid);
    if (tid < 128) pfB = aload64(hop2 + 256 + tid);
    pfC = aload64(hop1 + tid);
    if (tid < 128) pfD = aload64(hop1 + 256 + tid);
  }

  int cur = 0, prv = dil - 1;
  for (int t = 0; t < T_STEPS; ++t){
    const int slot = t & (RD-1);

    // ---- preamble: drain (prefetch loads + prior hop stores) ----
    asm volatile("s_waitcnt vmcnt(0)" ::: "memory");
    if (stage > 0){
      const bool bad = (fvU < (uint)(t+3)) || (stage==3 && fvU1 < (uint)(t+3));
      if (bad){
        if (lane == 0){
          while (aload32(up_prod) < (uint)(t+1)) __builtin_amdgcn_s_sleep(2);
          if (stage == 3)
            while (aload32(up_prod1) < (uint)(t+1)) __builtin_amdgcn_s_sleep(2);
        }
        // reconverged: flag confirmed -> reload data for THIS step
        if (stage < 3){
          const u64* s = hop_in + (size_t)(slot*64 + rep)*384;
          pfA = aload64(s + tid);
          if (tid < 128) pfB = aload64(s + 256 + tid);
        } else {
          const u64* s2 = hop2 + (size_t)(slot*64 + rep)*384;
          const u64* s1 = hop1 + (size_t)(slot*64 + rep)*384;
          pfA = aload64(s2 + tid);
          if (tid < 128) pfB = aload64(s2 + 256 + tid);
          pfC = aload64(s1 + tid);
          if (tid < 128) pfD = aload64(s1 + 256 + tid);
        }
        asm volatile("s_waitcnt vmcnt(0)" ::: "memory");
      }
    }
    // ---- stage prefetched data to LDS ----
    if (stage == 0){
      const int r = tid >> 6, c = tid & 63;
      ushort hb0 = f2bf(xv0);
      xh_hi[r*XS + c] = hb0;       xh_lo[r*XS + c] = f2bf(xv0 - bf2f(hb0));
      ushort hb1 = f2bf(xv1);
      xh_hi[(r+4)*XS + c] = hb1;   xh_lo[(r+4)*XS + c] = f2bf(xv1 - bf2f(hb1));
    } else {
      // u64 q in [0,384): q<192 -> hi plane, else lo plane; row q/24, col4 (q%24)*4
      {
        const int q = tid, qq = (q < 192) ? q : q - 192;
        ushort* plane = (q < 192) ? xh_hi : xh_lo;
        *(u64*)(plane + (qq/24)*XS + (qq%24)*4) = pfA;
      }
      if (tid < 128){
        const int q = tid + 256, qq = q - 192;
        *(u64*)(xh_lo + (qq/24)*XS + (qq%24)*4) = pfB;
      }
      if (stage == 3){
        *(u64*)(o1p + 4*tid) = pfC;
        if (tid < 128) *(u64*)(o1p + 4*(tid + 256)) = pfD;
      }
    }
    // h-copy: prev_h -> cols [KIN,KIN+32), del_h -> cols [KIN+32,KIN+64)
    {
      const int r = tid >> 5, c = tid & 31;   // r 0..7, c 0..31
      xh_hi[r*XS + KIN + c] = h_hi[prv*(NB*32) + r*32 + c];
      xh_lo[r*XS + KIN + c] = h_lo[prv*(NB*32) + r*32 + c];
      const int ss = (t >= dil) ? cur : prv;
      xh_hi[r*XS + KIN + 32 + c] = h_hi[ss*(NB*32) + r*32 + c];
      xh_lo[r*XS + KIN + 32 + c] = h_lo[ss*(NB*32) + r*32 + c];
    }
    __syncthreads();   // B1 (every wave did vmcnt(0) -> stores of t-1 drained)
    if (tid == 0){
      if (stage > 0){
        astore32(my_consA, (uint)(t+1));
        if (stage == 3) astore32(my_consB, (uint)(t+1));
      }
      if (stage < 3 && t >= 1) astore32(my_prod, (uint)t);  // data <= t-1 valid
    }
    // stage3: deferred y store (step t-1's projection, staged in yst)
    if (stage == 3 && t > 0){
      y_out[(size_t)((t-1)*BATCH + b0r + (tid>>6))*64 + (tid&63)] = yst[tid];
      y_out[(size_t)((t-1)*BATCH + b0r + (tid>>6) + 4)*64 + (tid&63)] = yst[tid + 256];
    }
    // ---- issue prefetch (data + flags) for t+1; hides under GEMM+gates ----
    const bool pre = (t + 1 < T_STEPS);
    if (pre){
      const int ns = (t + 1) & (RD-1);
      if (stage == 0){
        xv0 = x[(size_t)((t+1)*BATCH + b0r + (tid>>6))*64 + (tid&63)];
        xv1 = x[(size_t)((t+1)*BATCH + b0r + (tid>>6) + 4)*64 + (tid&63)];
      } else if (stage < 3){
        const u64* s = hop_in + (size_t)(ns*64 + rep)*384;
        pfA = aload64(s + tid);
        if (tid < 128) pfB = aload64(s + 256 + tid);
        fvU = aload32(up_prod);
      } else {
        const u64* s2 = hop2 + (size_t)(ns*64 + rep)*384;
        const u64* s1 = hop1 + (size_t)(ns*64 + rep)*384;
        pfA = aload64(s2 + tid);
        if (tid < 128) pfB = aload64(s2 + 256 + tid);
        pfC = aload64(s1 + tid);
        if (tid < 128) pfD = aload64(s1 + 256 + tid);
        fvU  = aload32(up_prod);
        fvU1 = aload32(up_prod1);
      }
    }
    if (stage < 3) fvDA = aload32(dnA);
    if (stage == 1) fvDB = aload32(dnB);
    asm volatile("" ::: "memory");

    // ---- GEMM: g = xh @ W^T + b  (pure ds_read + MFMA; 2 groups/wave) ----
    f32x4 acc[2][4];
    #pragma unroll
    for (int g = 0; g < 2; ++g)
      #pragma unroll
      for (int j = 0; j < 4; ++j)
        acc[g][j] = (f32x4){bias[g][j],bias[g][j],bias[g][j],bias[g][j]};
    const int abase = l15*XS + hi*8;
    #pragma unroll
    for (int ks = 0; ks < 5; ++ks){
      if (ks*32 < K){
        bf16x8 ahi = *(const bf16x8*)(xh_hi + abase + ks*32);
        bf16x8 alo = *(const bf16x8*)(xh_lo + abase + ks*32);
        #pragma unroll
        for (int g = 0; g < 2; ++g){
          #pragma unroll
          for (int j = 0; j < 4; ++j){
            acc[g][j] = __builtin_amdgcn_mfma_f32_16x16x32_bf16(ahi, whi[g][j][ks], acc[g][j], 0, 0, 0);
            acc[g][j] = __builtin_amdgcn_mfma_f32_16x16x32_bf16(alo, whi[g][j][ks], acc[g][j], 0, 0, 0);
            acc[g][j] = __builtin_amdgcn_mfma_f32_16x16x32_bf16(ahi, wlo[g][j][ks], acc[g][j], 0, 0, 0);
          }
        }
      }
    }

    // ---- gates + state update (lane owns states sidx, sidx+16; rows hi*4..+3) ----
    const bool has_prev = (t >= 1), has_del = (t >= dil);
    #pragma unroll
    for (int g = 0; g < 2; ++g){
      const int sg = sidx + 16*g;
      f32x4 pc = *(const f32x4*)(sh_c + prv*(128*CSTR) + sg*CSTR + (hi&1)*4);
      f32x4 dc = *(const f32x4*)(sh_c + cur*(128*CSTR) + sg*CSTR + (hi&1)*4);
      f32x4 ncv; float whv[4];
      #pragma unroll
      for (int k = 0; k < 4; ++k){
        float f  = sigm(acc[g][0][k] + 1.0f);
        float cd = tanh_fast(acc[g][1][k]);
        float al = sigm(acc[g][2][k]);
        float og = sigm(acc[g][3][k]);
        float wt = has_del ? (al*pc[k] + (1.0f - al)*dc[k]) : pc[k];
        float nc = has_prev ? (f*wt + (1.0f - f)*cd) : cd;
        ncv[k] = nc;
        whv[k] = og * nc;
      }
      if (hi < 2){
        *(f32x4*)(sh_c + cur*(128*CSTR) + sg*CSTR + hi*4) = ncv;
        #pragma unroll
        for (int k = 0; k < 4; ++k){
          const int r = hi*4 + k;
          const float w = whv[k];
          if (sg < OUTC){
            if (stage == 3){
              o3f[r*OUTC + sg] = w;
            } else {
              ushort hb = f2bf(w);
              outp[r*OUTC + sg]       = hb;
              outp[768 + r*OUTC + sg] = f2bf(w - bf2f(hb));
            }
          } else {
            ushort hb = f2bf(w);
            h_hi[cur*(NB*32) + r*32 + (sg - OUTC)] = hb;
            h_lo[cur*(NB*32) + r*32 + (sg - OUTC)] = f2bf(w - bf2f(hb));
          }
        }
      }
    }
    __syncthreads();   // B2

    // ---- stage output ----
    if (stage < 3){
      if (t >= RD){
        const bool badc = (fvDA < (uint)(t-13)) || (stage==1 && fvDB < (uint)(t-13));
        if (badc){
          if (lane == 0){
            while (aload32(dnA) < (uint)(t-15)) __builtin_amdgcn_s_sleep(2);
            if (stage == 1)
              while (aload32(dnB) < (uint)(t-15)) __builtin_amdgcn_s_sleep(2);
          }
        }
      }
      u64* dst = hop_out + (size_t)(slot*64 + rep)*384;
      astore64(dst + tid, *(const u64*)(outp + 4*tid));               // fire & forget
      if (tid < 128) astore64(dst + 256 + tid, *(const u64*)(outp + 4*(tid + 256)));
    } else {
      // resnet: pb = out3 + out1 -> PA planes in outp
      for (int j = tid; j < 768; j += 256){
        float v = o3f[j] + bf2f(o1p[j]) + bf2f(o1p[768 + j]);
        ushort hb = f2bf(v);
        outp[j]       = hb;
        outp[768 + j] = f2bf(v - bf2f(hb));
      }
      __syncthreads(); // B3
      {
        f32x4 acc1 = (f32x4){bav, bav, bav, bav};
        const int pbase = l15*96 + hi*8;
        #pragma unroll
        for (int ks = 0; ks < 3; ++ks){
          bf16x8 ahi = *(const bf16x8*)(outp + pbase + ks*32);
          bf16x8 alo = *(const bf16x8*)(outp + 768 + pbase + ks*32);
          acc1 = __builtin_amdgcn_mfma_f32_16x16x32_bf16(ahi, phi[ks], acc1, 0, 0, 0);
          acc1 = __builtin_amdgcn_mfma_f32_16x16x32_bf16(alo, phi[ks], acc1, 0, 0, 0);
          acc1 = __builtin_amdgcn_mfma_f32_16x16x32_bf16(ahi, plo[ks], acc1, 0, 0, 0);
        }
        if (hi < 2){
          const int ocol = 16*wv + l15;
          #pragma unroll
          for (int k = 0; k < 4; ++k){
            yst[(hi*4 + k)*64 + ocol] = acc1[k];   // deferred to next step's y store
          }
        }
      }
    }
    prv = cur;
    cur = (cur + 1 == dil) ? 0 : cur + 1;
  }

  // ---- postloop: drain, final deferred y, terminal flags ----
  asm volatile("s_waitcnt vmcnt(0)" ::: "memory");
  __syncthreads();
  if (stage == 3){
    y_out[(size_t)((T_STEPS-1)*BATCH + b0r + (tid>>6))*64 + (tid&63)] = yst[tid];
    y_out[(size_t)((T_STEPS-1)*BATCH + b0r + (tid>>6) + 4)*64 + (tid&63)] = yst[tid + 256];
  }
  if (stage < 3 && tid == 0) astore32(my_prod, (uint)(T_STEPS + 3));
}

extern "C" void kernel_launch(void* const* d_in, const int* in_sizes, int n_in,
                              void* d_out, int out_size, void* d_ws, size_t ws_size,
                              hipStream_t stream) {
  (void)in_sizes; (void)n_in; (void)out_size; (void)ws_size;
  const float* x  = (const float*)d_in[0];
  const float* W0 = (const float*)d_in[1];
  const float* b0 = (const float*)d_in[2];
  const float* W1 = (const float*)d_in[3];
  const float* b1 = (const float*)d_in[4];
  const float* W2 = (const float*)d_in[5];
  const float* b2 = (const float*)d_in[6];
  const float* W3 = (const float*)d_in[7];
  const float* b3 = (const float*)d_in[8];
  const float* Wa = (const float*)d_in[9];
  const float* ba = (const float*)d_in[10];
  float* out = (float*)d_out;

  // Flags: 128B line each. prod[3][64] @0, consA[3][64] @24576, consB[64] @49152.
  uint* prod  = (uint*)d_ws;
  uint* consA = (uint*)((char*)d_ws + 24576);
  uint* consB = (uint*)((char*)d_ws + 49152);
  u64* hop0 = (u64*)((char*)d_ws + 65536);   // [RD][64][384] u64 (hi/lo planes)
  u64* hop1 = hop0 + (size_t)RD*64*384;
  u64* hop2 = hop1 + (size_t)RD*64*384;

  hipMemsetAsync(d_ws, 0, 65536, stream);  // re-zero flags every call
  hipLaunchKernelGGL(rnn_pipeline, dim3(256), dim3(256), 0, stream,
                     x, W0, b0, W1, b1, W2, b2, W3, b3, Wa, ba,
                     out, prod, consA, consB, hop0, hop1, hop2);
}

// Round 9
// 2559.789 us; speedup vs baseline: 1.1475x; 1.1475x over previous
//
#include <hip/hip_runtime.h>

typedef unsigned int uint;
typedef unsigned short ushort;
typedef unsigned long long u64;
typedef __attribute__((ext_vector_type(8))) short bf16x8;
typedef __attribute__((ext_vector_type(4))) float f32x4;

// Problem constants
#define T_STEPS 512
#define BATCH   512
#define NB      8       // batch rows per replica
#define RD      16      // inter-stage ring depth (power of 2)
#define XS      168     // xh plane row stride (ushort)
#define CSTR    12      // c-ring pad: floats per (slot,sidx) row
#define OUTC    96
#define FSTR    32      // flag stride in uints (128B line per flag)

__device__ __forceinline__ ushort f2bf(float f){
  uint u = __builtin_bit_cast(uint, f);
  u = (u + 0x7FFFu + ((u >> 16) & 1u)) >> 16;   // RNE
  return (ushort)u;
}
__device__ __forceinline__ float bf2f(ushort h){
  uint u = ((uint)h) << 16; return __builtin_bit_cast(float, u);
}
__device__ __forceinline__ float sigm(float x){
  float e = __builtin_exp2f(-1.44269504f * x);
  return __builtin_amdgcn_rcpf(1.0f + e);
}
__device__ __forceinline__ float tanh_fast(float x){
  float e = __builtin_exp2f(-2.88539008f * x);
  return 2.0f * __builtin_amdgcn_rcpf(1.0f + e) - 1.0f;
}
// Relaxed agent-scope atomics: LLC-coherent, no L1/L2 invalidate/writeback.
__device__ __forceinline__ uint aload32(const uint* p){
  return __hip_atomic_load(p, __ATOMIC_RELAXED, __HIP_MEMORY_SCOPE_AGENT);
}
__device__ __forceinline__ void astore32(uint* p, uint v){
  __hip_atomic_store(p, v, __ATOMIC_RELAXED, __HIP_MEMORY_SCOPE_AGENT);
}
__device__ __forceinline__ u64 aload64(const u64* p){
  return __hip_atomic_load(p, __ATOMIC_RELAXED, __HIP_MEMORY_SCOPE_AGENT);
}
__device__ __forceinline__ void astore64(u64* p, u64 v){
  __hip_atomic_store(p, v, __ATOMIC_RELAXED, __HIP_MEMORY_SCOPE_AGENT);
}

// 4-stage pipeline (stage = blockIdx.x>>6, rep = blockIdx.x&63), NB=8 rows.
// 2-STEP-DEEP prefetch: data loads for step t+2 issued at step t into
// parity-selected register buffers (wave-uniform t&1 branches, never selects).
// NO manual vmcnt in the loop: compiler inserts precise per-register waits, so
// the staging wait covers only 2-step-old loads while hop stores stay in
// flight. Producer flag V=t-2 at B1(t) is proven safe by in-order vmcnt
// retirement (waiting loads(t) retires stores(t-3)). Optimistic flag checks
// with 1-step-old samples; blocking fallbacks on monotone counters.
__global__ __launch_bounds__(512, 1)
void rnn_pipeline(const float* __restrict__ x,
                  const float* __restrict__ W0, const float* __restrict__ b0,
                  const float* __restrict__ W1, const float* __restrict__ b1,
                  const float* __restrict__ W2, const float* __restrict__ b2,
                  const float* __restrict__ W3, const float* __restrict__ b3,
                  const float* __restrict__ Wa, const float* __restrict__ ba,
                  float* __restrict__ y_out,
                  uint* __restrict__ prod, uint* __restrict__ consA,
                  uint* __restrict__ consB,
                  u64* __restrict__ hop0, u64* __restrict__ hop1,
                  u64* __restrict__ hop2)
{
  const int tid  = threadIdx.x;
  const int wv   = tid >> 6;      // wave 0..7
  const int lane = tid & 63;
  const int l15  = lane & 15;
  const int hi   = lane >> 4;     // 0..3
  const int rep  = blockIdx.x & 63;
  const int stage= blockIdx.x >> 6;
  const int b0r  = rep * NB;

  const int dil = (stage==0)?1:(stage==1)?3:(stage==2)?6:12;
  const int KIN = (stage==0)?64:96;
  const int K   = KIN + 64;
  const float* Wl = (stage==0)?W0:(stage==1)?W1:(stage==2)?W2:W3;
  const float* bl = (stage==0)?b0:(stage==1)?b1:(stage==2)?b2:b3;

  __shared__ __align__(16) ushort xh_hi[16*XS], xh_lo[16*XS];  // A-operand planes
  __shared__ __align__(16) float  sh_c[12*128*CSTR];           // c ring [slot][sidx][12]
  __shared__ __align__(16) ushort h_hi[12*NB*32], h_lo[12*NB*32]; // h ring planes
  __shared__ __align__(16) ushort outp[2304];  // [hi 768][lo 768] (+proj overread pad)
  __shared__ __align__(16) ushort o1p[1536];   // stage3: out1 planes
  __shared__ __align__(16) float  o3f[NB*OUTC];// stage3: out3 fp32
  __shared__ __align__(16) float  yst[512];    // stage3: deferred y (step t-1)

  for (int i = tid; i < 16*XS; i += 512){ xh_hi[i] = 0; xh_lo[i] = 0; }
  for (int i = tid; i < 12*128*CSTR; i += 512) sh_c[i] = 0.0f;
  for (int i = tid; i < 12*NB*32; i += 512){ h_hi[i] = 0; h_lo[i] = 0; }
  for (int i = tid; i < 2304; i += 512) outp[i] = 0;
  for (int i = tid; i < 1536; i += 512) o1p[i] = 0;
  for (int i = tid; i < NB*OUTC; i += 512) o3f[i] = 0.0f;
  yst[tid] = 0.0f;

  const int sidx = 16*wv + l15;  // state index 0..127 owned by this lane

  // Layer weights as split-bf16 MFMA B-fragments (zero-padded past K).
  bf16x8 whi[4][5], wlo[4][5];
  #pragma unroll
  for (int j = 0; j < 4; ++j){
    const int grow = 128*j + sidx;
    #pragma unroll
    for (int ks = 0; ks < 5; ++ks){
      bf16x8 vh, vl;
      const int cb = ks*32 + hi*8;
      if (cb < K){
        const float* p = Wl + (size_t)grow*K + cb;
        #pragma unroll
        for (int i = 0; i < 8; ++i){
          float w = p[i];
          ushort h = f2bf(w);
          vh[i] = (short)h;
          vl[i] = (short)f2bf(w - bf2f(h));
        }
      } else {
        #pragma unroll
        for (int i = 0; i < 8; ++i){ vh[i] = 0; vl[i] = 0; }
      }
      whi[j][ks] = vh; wlo[j][ks] = vl;
    }
  }
  float bias[4];
  #pragma unroll
  for (int j = 0; j < 4; ++j) bias[j] = bl[128*j + sidx];

  // Projection weights (stage3, waves 0..3)
  bf16x8 phi[3], plo[3];
  #pragma unroll
  for (int ks = 0; ks < 3; ++ks){
    bf16x8 z;
    #pragma unroll
    for (int i = 0; i < 8; ++i) z[i]=0;
    phi[ks]=z; plo[ks]=z;
  }
  float bav = 0.0f;
  if (stage == 3 && wv < 4){
    const int ocol = 16*wv + l15;
    #pragma unroll
    for (int ks = 0; ks < 3; ++ks){
      const float* p = Wa + (size_t)ocol*96 + ks*32 + hi*8;
      bf16x8 vh, vl;
      #pragma unroll
      for (int i = 0; i < 8; ++i){
        float w = p[i];
        ushort h = f2bf(w);
        vh[i] = (short)h;
        vl[i] = (short)f2bf(w - bf2f(h));
      }
      phi[ks] = vh; plo[ks] = vl;
    }
    bav = ba[ocol];
  }

  // Flag wiring (each flag on its own 128B line)
  uint* up_prod  = (stage==1)? &prod[rep*FSTR] : (stage==2)? &prod[(64+rep)*FSTR] :
                   (stage==3)? &prod[(128+rep)*FSTR] : nullptr;
  uint* up_prod1 = (stage==3)? &prod[(64+rep)*FSTR] : nullptr;
  uint* my_prod  = (stage==0)? &prod[rep*FSTR] : (stage==1)? &prod[(64+rep)*FSTR] :
                   (stage==2)? &prod[(128+rep)*FSTR] : nullptr;
  uint* my_consA = (stage==1)? &consA[rep*FSTR] : (stage==2)? &consA[(64+rep)*FSTR] :
                   (stage==3)? &consA[(128+rep)*FSTR] : nullptr;
  uint* my_consB = (stage==3)? &consB[rep*FSTR] : nullptr;
  uint* dnA      = (stage==0)? &consA[rep*FSTR] : (stage==1)? &consA[(64+rep)*FSTR] :
                   (stage==2)? &consA[(128+rep)*FSTR] : nullptr;
  uint* dnB      = (stage==1)? &consB[rep*FSTR] : nullptr;
  const u64* hop_in  = (stage==1)? hop0 : (stage==2)? hop1 : nullptr;
  u64*       hop_out = (stage==0)? hop0 : (stage==1)? hop1 : (stage==2)? hop2 : nullptr;

  // prefetch helpers (distinct inline sites per parity keep regs separate)
  auto issueS12 = [&](u64& A, int sl){
    if (tid < 384) A = aload64(hop_in + (size_t)(sl*64 + rep)*384 + tid);
  };
  auto issueS3 = [&](u64& A, u64& B, int sl){
    const u64* s2 = hop2 + (size_t)(sl*64 + rep)*384;
    const u64* s1 = hop1 + (size_t)(sl*64 + rep)*384;
    A = (tid < 384) ? aload64(s2 + tid) : aload64(s1 + (tid - 384));
    if (tid < 256) B = aload64(s1 + 128 + tid);
  };
  auto stageS12 = [&](u64 A){
    if (tid < 384){
      const int q = (tid < 192) ? tid : tid - 192;
      ushort* pl = (tid < 192) ? xh_hi : xh_lo;
      *(u64*)(pl + (q/24)*XS + (q%24)*4) = A;
    }
  };
  auto stageS3 = [&](u64 A, u64 B){
    if (tid < 384){
      const int q = (tid < 192) ? tid : tid - 192;
      ushort* pl = (tid < 192) ? xh_hi : xh_lo;
      *(u64*)(pl + (q/24)*XS + (q%24)*4) = A;
    } else {
      *(u64*)(o1p + 4*(tid - 384)) = A;
    }
    if (tid < 256) *(u64*)(o1p + 4*(128 + tid)) = B;
  };

  __syncthreads();

  // ---- preloop: prime BOTH parity buffers (slots 0 and 1) ----
  u64 pfA0 = 0, pfB0 = 0, pfA1 = 0, pfB1 = 0;
  float xv0 = 0.0f, xv1 = 0.0f;
  uint fvU = 0, fvU1 = 0, fvDA = 0, fvDB = 0;
  if (stage == 0){
    xv0 = x[(size_t)(b0r + (tid>>6))*64 + (tid&63)];
    xv1 = x[(size_t)(BATCH + b0r + (tid>>6))*64 + (tid&63)];
  } else {
    do { fvU = aload32(up_prod); if (fvU < 4u) __builtin_amdgcn_s_sleep(2); } while (fvU < 4u);
    if (stage == 3){
      do { fvU1 = aload32(up_prod1); if (fvU1 < 4u) __builtin_amdgcn_s_sleep(2); } while (fvU1 < 4u);
    }
    if (stage < 3){ issueS12(pfA0, 0); issueS12(pfA1, 1); }
    else          { issueS3(pfA0, pfB0, 0); issueS3(pfA1, pfB1, 1); }
  }

  int cur = 0, prv = dil - 1;
  for (int t = 0; t < T_STEPS; ++t){
    const int slot = t & (RD-1);
    const bool even = ((t & 1) == 0);

    // ---- preamble: optimistic upstream validity (data waits are compiler-precise) ----
    if (stage > 0){
      const bool bad = (fvU < (uint)(t+3)) || (stage == 3 && fvU1 < (uint)(t+3));
      if (bad){
        if (lane == 0){
          while (aload32(up_prod) < (uint)(t+1)) __builtin_amdgcn_s_sleep(2);
          if (stage == 3)
            while (aload32(up_prod1) < (uint)(t+1)) __builtin_amdgcn_s_sleep(2);
        }
        if (stage < 3){ if (even) issueS12(pfA0, slot); else issueS12(pfA1, slot); }
        else { if (even) issueS3(pfA0, pfB0, slot); else issueS3(pfA1, pfB1, slot); }
      }
    }
    // ---- stage parity buffer to LDS ----
    if (stage == 0){
      const int r = tid >> 6, c = tid & 63;
      if (even){
        ushort hb = f2bf(xv0);
        xh_hi[r*XS + c] = hb; xh_lo[r*XS + c] = f2bf(xv0 - bf2f(hb));
      } else {
        ushort hb = f2bf(xv1);
        xh_hi[r*XS + c] = hb; xh_lo[r*XS + c] = f2bf(xv1 - bf2f(hb));
      }
    } else {
      if (even){ if (stage < 3) stageS12(pfA0); else stageS3(pfA0, pfB0); }
      else     { if (stage < 3) stageS12(pfA1); else stageS3(pfA1, pfB1); }
    }
    // h-copy: prev_h -> cols [KIN,KIN+32), del_h -> cols [KIN+32,KIN+64)
    {
      const int which = tid >> 8, rem = tid & 255, r = rem >> 5, c = rem & 31;
      const int srcslot = (which == 1 && t >= dil) ? cur : prv;
      xh_hi[r*XS + KIN + which*32 + c] = h_hi[srcslot*(NB*32) + r*32 + c];
      xh_lo[r*XS + KIN + which*32 + c] = h_lo[srcslot*(NB*32) + r*32 + c];
    }
    __syncthreads();   // B1
    if (tid == 0){
      if (stage > 0){
        astore32(my_consA, (uint)(t+1));
        if (stage == 3) astore32(my_consB, (uint)(t+1));
      }
      if (stage < 3 && t >= 2) astore32(my_prod, (uint)(t-2));  // slots <= t-3 proven
    }
    // stage3: deferred y store (step t-1's projection, staged in yst)
    if (stage == 3 && t > 0){
      y_out[(size_t)((t-1)*BATCH + b0r + (tid>>6))*64 + (tid&63)] = yst[tid];
    }
    // ---- downstream availability check (uses LAST step's samples; no wait) ----
    if (stage < 3 && t >= RD){
      const bool badc = (fvDA < (uint)(t-14)) || (stage == 1 && fvDB < (uint)(t-14));
      if (badc){
        if (lane == 0){
          while (aload32(dnA) < (uint)(t-15)) __builtin_amdgcn_s_sleep(2);
          if (stage == 1)
            while (aload32(dnB) < (uint)(t-15)) __builtin_amdgcn_s_sleep(2);
        }
      }
    }
    // ---- issue prefetch for t+2 + refresh flag samples (hide = 2 full steps) ----
    if (t + 2 < T_STEPS){
      const int ns = (t + 2) & (RD-1);
      if (stage == 0){
        if (even) xv0 = x[(size_t)((t+2)*BATCH + b0r + (tid>>6))*64 + (tid&63)];
        else      xv1 = x[(size_t)((t+2)*BATCH + b0r + (tid>>6))*64 + (tid&63)];
      } else if (stage < 3){
        if (even) issueS12(pfA0, ns); else issueS12(pfA1, ns);
      } else {
        if (even) issueS3(pfA0, pfB0, ns); else issueS3(pfA1, pfB1, ns);
      }
    }
    if (stage > 0){ fvU = aload32(up_prod); if (stage == 3) fvU1 = aload32(up_prod1); }
    if (stage < 3) fvDA = aload32(dnA);
    if (stage == 1) fvDB = aload32(dnB);
    asm volatile("" ::: "memory");   // pin load issue before GEMM

    // ---- GEMM: g = xh @ W^T + b  (pure ds_read + MFMA) ----
    f32x4 acc[4];
    #pragma unroll
    for (int j = 0; j < 4; ++j) acc[j] = (f32x4){bias[j],bias[j],bias[j],bias[j]};
    const int abase = l15*XS + hi*8;
    #pragma unroll
    for (int ks = 0; ks < 5; ++ks){
      if (ks*32 < K){
        bf16x8 ahi = *(const bf16x8*)(xh_hi + abase + ks*32);
        bf16x8 alo = *(const bf16x8*)(xh_lo + abase + ks*32);
        #pragma unroll
        for (int j = 0; j < 4; ++j){
          acc[j] = __builtin_amdgcn_mfma_f32_16x16x32_bf16(ahi, whi[j][ks], acc[j], 0, 0, 0);
          acc[j] = __builtin_amdgcn_mfma_f32_16x16x32_bf16(alo, whi[j][ks], acc[j], 0, 0, 0);
          acc[j] = __builtin_amdgcn_mfma_f32_16x16x32_bf16(ahi, wlo[j][ks], acc[j], 0, 0, 0);
        }
      }
    }

    // ---- gates + state update (lane owns state sidx, rows hi*4..hi*4+3) ----
    f32x4 pc = *(const f32x4*)(sh_c + prv*(128*CSTR) + sidx*CSTR + (hi&1)*4);
    f32x4 dc = *(const f32x4*)(sh_c + cur*(128*CSTR) + sidx*CSTR + (hi&1)*4);
    const bool has_prev = (t >= 1), has_del = (t >= dil);
    f32x4 ncv; float whv[4];
    #pragma unroll
    for (int k = 0; k < 4; ++k){
      float f  = sigm(acc[0][k] + 1.0f);
      float cd = tanh_fast(acc[1][k]);
      float al = sigm(acc[2][k]);
      float og = sigm(acc[3][k]);
      float wt = has_del ? (al*pc[k] + (1.0f - al)*dc[k]) : pc[k];
      float nc = has_prev ? (f*wt + (1.0f - f)*cd) : cd;
      ncv[k] = nc;
      whv[k] = og * nc;
    }
    if (hi < 2){
      *(f32x4*)(sh_c + cur*(128*CSTR) + sidx*CSTR + hi*4) = ncv;
      #pragma unroll
      for (int k = 0; k < 4; ++k){
        const int r = hi*4 + k;
        const float w = whv[k];
        if (sidx < OUTC){
          if (stage == 3){
            o3f[r*OUTC + sidx] = w;
          } else {
            ushort hb = f2bf(w);
            outp[r*OUTC + sidx]       = hb;
            outp[768 + r*OUTC + sidx] = f2bf(w - bf2f(hb));
          }
        } else {
          ushort hb = f2bf(w);
          h_hi[cur*(NB*32) + r*32 + (sidx - OUTC)] = hb;
          h_lo[cur*(NB*32) + r*32 + (sidx - OUTC)] = f2bf(w - bf2f(hb));
        }
      }
    }
    __syncthreads();   // B2

    // ---- stage output ----
    if (stage < 3){
      // single trailing store instr per wave (48 lanes each); fire & forget
      if (lane < 48){
        const int g = wv*48 + lane;
        u64 v = *(const u64*)(outp + 4*g);
        astore64(hop_out + (size_t)(slot*64 + rep)*384 + g, v);
      }
    } else {
      // resnet: pb = out3 + out1 -> PA planes in outp
      for (int j = tid; j < 768; j += 512){
        float v = o3f[j] + bf2f(o1p[j]) + bf2f(o1p[768 + j]);
        ushort hb = f2bf(v);
        outp[j]       = hb;
        outp[768 + j] = f2bf(v - bf2f(hb));
      }
      __syncthreads(); // B3
      if (wv < 4){
        f32x4 acc1 = (f32x4){bav, bav, bav, bav};
        const int pbase = l15*96 + hi*8;
        #pragma unroll
        for (int ks = 0; ks < 3; ++ks){
          bf16x8 ahi = *(const bf16x8*)(outp + pbase + ks*32);
          bf16x8 alo = *(const bf16x8*)(outp + 768 + pbase + ks*32);
          acc1 = __builtin_amdgcn_mfma_f32_16x16x32_bf16(ahi, phi[ks], acc1, 0, 0, 0);
          acc1 = __builtin_amdgcn_mfma_f32_16x16x32_bf16(alo, phi[ks], acc1, 0, 0, 0);
          acc1 = __builtin_amdgcn_mfma_f32_16x16x32_bf16(ahi, plo[ks], acc1, 0, 0, 0);
        }
        if (hi < 2){
          const int ocol = 16*wv + l15;
          #pragma unroll
          for (int k = 0; k < 4; ++k){
            yst[(hi*4 + k)*64 + ocol] = acc1[k];   // deferred to next step's y store
          }
        }
      }
    }
    prv = cur;
    cur = (cur + 1 == dil) ? 0 : cur + 1;
  }

  // ---- postloop: drain, final deferred y, terminal flags ----
  asm volatile("s_waitcnt vmcnt(0)" ::: "memory");
  __syncthreads();
  if (stage == 3){
    y_out[(size_t)((T_STEPS-1)*BATCH + b0r + (tid>>6))*64 + (tid&63)] = yst[tid];
  }
  if (stage < 3 && tid == 0) astore32(my_prod, (uint)(T_STEPS + 3));
}

extern "C" void kernel_launch(void* const* d_in, const int* in_sizes, int n_in,
                              void* d_out, int out_size, void* d_ws, size_t ws_size,
                              hipStream_t stream) {
  (void)in_sizes; (void)n_in; (void)out_size; (void)ws_size;
  const float* x  = (const float*)d_in[0];
  const float* W0 = (const float*)d_in[1];
  const float* b0 = (const float*)d_in[2];
  const float* W1 = (const float*)d_in[3];
  const float* b1 = (const float*)d_in[4];
  const float* W2 = (const float*)d_in[5];
  const float* b2 = (const float*)d_in[6];
  const float* W3 = (const float*)d_in[7];
  const float* b3 = (const float*)d_in[8];
  const float* Wa = (const float*)d_in[9];
  const float* ba = (const float*)d_in[10];
  float* out = (float*)d_out;

  // Flags: 128B line each. prod[3][64] @0, consA[3][64] @24576, consB[64] @49152.
  uint* prod  = (uint*)d_ws;
  uint* consA = (uint*)((char*)d_ws + 24576);
  uint* consB = (uint*)((char*)d_ws + 49152);
  u64* hop0 = (u64*)((char*)d_ws + 65536);   // [RD][64][384] u64 (hi/lo planes)
  u64* hop1 = hop0 + (size_t)RD*64*384;
  u64* hop2 = hop1 + (size_t)RD*64*384;

  hipMemsetAsync(d_ws, 0, 65536, stream);  // re-zero flags every call
  hipLaunchKernelGGL(rnn_pipeline, dim3(256), dim3(512), 0, stream,
                     x, W0, b0, W1, b1, W2, b2, W3, b3, Wa, ba,
                     out, prod, consA, consB, hop0, hop1, hop2);
}

// Round 10
// 2205.098 us; speedup vs baseline: 1.3321x; 1.1609x over previous
//
#include <hip/hip_runtime.h>

typedef unsigned int uint;
typedef unsigned short ushort;
typedef unsigned long long u64;
typedef __attribute__((ext_vector_type(8))) short bf16x8;
typedef __attribute__((ext_vector_type(4))) float f32x4;

// Problem constants
#define T_STEPS 512
#define BATCH   512
#define NB      8       // batch rows per replica
#define XS      168     // xh plane row stride (ushort)
#define CSTR    12      // c-ring pad: floats per (slot,sidx) row
#define OUTC    96
#define FSTR    32      // flag stride in uints (128B line per flag)

__device__ __forceinline__ ushort f2bf(float f){
  uint u = __builtin_bit_cast(uint, f);
  u = (u + 0x7FFFu + ((u >> 16) & 1u)) >> 16;   // RNE
  return (ushort)u;
}
__device__ __forceinline__ float bf2f(ushort h){
  uint u = ((uint)h) << 16; return __builtin_bit_cast(float, u);
}
__device__ __forceinline__ float sigm(float x){
  float e = __builtin_exp2f(-1.44269504f * x);
  return __builtin_amdgcn_rcpf(1.0f + e);
}
__device__ __forceinline__ float tanh_fast(float x){
  float e = __builtin_exp2f(-2.88539008f * x);
  return 2.0f * __builtin_amdgcn_rcpf(1.0f + e) - 1.0f;
}
// Relaxed agent-scope atomics: LLC-coherent, no L1/L2 invalidate/writeback.
__device__ __forceinline__ uint aload32(const uint* p){
  return __hip_atomic_load(p, __ATOMIC_RELAXED, __HIP_MEMORY_SCOPE_AGENT);
}
__device__ __forceinline__ void astore32(uint* p, uint v){
  __hip_atomic_store(p, v, __ATOMIC_RELAXED, __HIP_MEMORY_SCOPE_AGENT);
}
__device__ __forceinline__ u64 aload64(const u64* p){
  return __hip_atomic_load(p, __ATOMIC_RELAXED, __HIP_MEMORY_SCOPE_AGENT);
}
__device__ __forceinline__ void astore64(u64* p, u64 v){
  __hip_atomic_store(p, v, __ATOMIC_RELAXED, __HIP_MEMORY_SCOPE_AGENT);
}

// 4-stage pipeline (stage = blockIdx.x>>6, rep = blockIdx.x&63), NB=8 rows.
// Runtime ring depth rd: when rd >= T_STEPS every step uses a unique slot,
// so ring-full can never happen -> downstream-full checks (the steady-state
// knife-edge LLC polls that throttled stages 0-2 every step) are eliminated
// and producers free-run. Consumers' upstream is then always far ahead and
// the optimistic flag checks always pass after warmup.
__global__ __launch_bounds__(512, 1)
void rnn_pipeline(const float* __restrict__ x,
                  const float* __restrict__ W0, const float* __restrict__ b0,
                  const float* __restrict__ W1, const float* __restrict__ b1,
                  const float* __restrict__ W2, const float* __restrict__ b2,
                  const float* __restrict__ W3, const float* __restrict__ b3,
                  const float* __restrict__ Wa, const float* __restrict__ ba,
                  float* __restrict__ y_out,
                  uint* __restrict__ prod, uint* __restrict__ consA,
                  uint* __restrict__ consB,
                  u64* __restrict__ hop0, u64* __restrict__ hop1,
                  u64* __restrict__ hop2, int rd)
{
  const int tid  = threadIdx.x;
  const int wv   = tid >> 6;      // wave 0..7
  const int lane = tid & 63;
  const int l15  = lane & 15;
  const int hi   = lane >> 4;     // 0..3
  const int rep  = blockIdx.x & 63;
  const int stage= blockIdx.x >> 6;
  const int b0r  = rep * NB;
  const int rmask= rd - 1;

  const int dil = (stage==0)?1:(stage==1)?3:(stage==2)?6:12;
  const int KIN = (stage==0)?64:96;
  const int K   = KIN + 64;
  const float* Wl = (stage==0)?W0:(stage==1)?W1:(stage==2)?W2:W3;
  const float* bl = (stage==0)?b0:(stage==1)?b1:(stage==2)?b2:b3;

  __shared__ __align__(16) ushort xh_hi[16*XS], xh_lo[16*XS];  // A-operand planes
  __shared__ __align__(16) float  sh_c[12*128*CSTR];           // c ring [slot][sidx][12]
  __shared__ __align__(16) ushort h_hi[12*NB*32], h_lo[12*NB*32]; // h ring planes
  __shared__ __align__(16) ushort outp[2304];  // [hi 768][lo 768] (+proj overread pad)
  __shared__ __align__(16) ushort o1p[1536];   // stage3: out1 planes
  __shared__ __align__(16) float  o3f[NB*OUTC];// stage3: out3 fp32
  __shared__ __align__(16) float  yst[512];    // stage3: deferred y (step t-1)

  for (int i = tid; i < 16*XS; i += 512){ xh_hi[i] = 0; xh_lo[i] = 0; }
  for (int i = tid; i < 12*128*CSTR; i += 512) sh_c[i] = 0.0f;
  for (int i = tid; i < 12*NB*32; i += 512){ h_hi[i] = 0; h_lo[i] = 0; }
  for (int i = tid; i < 2304; i += 512) outp[i] = 0;
  for (int i = tid; i < 1536; i += 512) o1p[i] = 0;
  for (int i = tid; i < NB*OUTC; i += 512) o3f[i] = 0.0f;
  yst[tid] = 0.0f;

  const int sidx = 16*wv + l15;  // state index 0..127 owned by this lane

  // Layer weights as split-bf16 MFMA B-fragments (zero-padded past K).
  bf16x8 whi[4][5], wlo[4][5];
  #pragma unroll
  for (int j = 0; j < 4; ++j){
    const int grow = 128*j + sidx;
    #pragma unroll
    for (int ks = 0; ks < 5; ++ks){
      bf16x8 vh, vl;
      const int cb = ks*32 + hi*8;
      if (cb < K){
        const float* p = Wl + (size_t)grow*K + cb;
        #pragma unroll
        for (int i = 0; i < 8; ++i){
          float w = p[i];
          ushort h = f2bf(w);
          vh[i] = (short)h;
          vl[i] = (short)f2bf(w - bf2f(h));
        }
      } else {
        #pragma unroll
        for (int i = 0; i < 8; ++i){ vh[i] = 0; vl[i] = 0; }
      }
      whi[j][ks] = vh; wlo[j][ks] = vl;
    }
  }
  float bias[4];
  #pragma unroll
  for (int j = 0; j < 4; ++j) bias[j] = bl[128*j + sidx];

  // Projection weights (stage3, waves 0..3)
  bf16x8 phi[3], plo[3];
  #pragma unroll
  for (int ks = 0; ks < 3; ++ks){
    bf16x8 z;
    #pragma unroll
    for (int i = 0; i < 8; ++i) z[i]=0;
    phi[ks]=z; plo[ks]=z;
  }
  float bav = 0.0f;
  if (stage == 3 && wv < 4){
    const int ocol = 16*wv + l15;
    #pragma unroll
    for (int ks = 0; ks < 3; ++ks){
      const float* p = Wa + (size_t)ocol*96 + ks*32 + hi*8;
      bf16x8 vh, vl;
      #pragma unroll
      for (int i = 0; i < 8; ++i){
        float w = p[i];
        ushort h = f2bf(w);
        vh[i] = (short)h;
        vl[i] = (short)f2bf(w - bf2f(h));
      }
      phi[ks] = vh; plo[ks] = vl;
    }
    bav = ba[ocol];
  }

  // Flag wiring (each flag on its own 128B line)
  uint* up_prod  = (stage==1)? &prod[rep*FSTR] : (stage==2)? &prod[(64+rep)*FSTR] :
                   (stage==3)? &prod[(128+rep)*FSTR] : nullptr;
  uint* up_prod1 = (stage==3)? &prod[(64+rep)*FSTR] : nullptr;
  uint* my_prod  = (stage==0)? &prod[rep*FSTR] : (stage==1)? &prod[(64+rep)*FSTR] :
                   (stage==2)? &prod[(128+rep)*FSTR] : nullptr;
  uint* my_consA = (stage==1)? &consA[rep*FSTR] : (stage==2)? &consA[(64+rep)*FSTR] :
                   (stage==3)? &consA[(128+rep)*FSTR] : nullptr;
  uint* my_consB = (stage==3)? &consB[rep*FSTR] : nullptr;
  uint* dnA      = (stage==0)? &consA[rep*FSTR] : (stage==1)? &consA[(64+rep)*FSTR] :
                   (stage==2)? &consA[(128+rep)*FSTR] : nullptr;
  uint* dnB      = (stage==1)? &consB[rep*FSTR] : nullptr;
  const u64* hop_in  = (stage==1)? hop0 : (stage==2)? hop1 : nullptr;
  u64*       hop_out = (stage==0)? hop0 : (stage==1)? hop1 : (stage==2)? hop2 : nullptr;

  __syncthreads();

  // ---- pre-loop prefetch for t = 0 ----
  u64 pfA = 0, pfB = 0; float xv = 0.0f;
  uint fvU = 0, fvU1 = 0, fvDA = 0, fvDB = 0;
  if (stage == 0){
    xv = x[(size_t)(b0r + (tid>>6))*64 + (tid&63)];
  } else if (stage < 3){
    uint f = aload32(up_prod);
    while (f < 1u){ __builtin_amdgcn_s_sleep(2); f = aload32(up_prod); }
    if (tid < 384) pfA = aload64(hop_in + (size_t)rep*384 + tid);
  } else {
    uint f = aload32(up_prod);
    while (f < 1u){ __builtin_amdgcn_s_sleep(2); f = aload32(up_prod); }
    f = aload32(up_prod1);
    while (f < 1u){ __builtin_amdgcn_s_sleep(2); f = aload32(up_prod1); }
    const u64* s2 = hop2 + (size_t)rep*384;
    const u64* s1 = hop1 + (size_t)rep*384;
    pfA = (tid < 384) ? aload64(s2 + tid) : aload64(s1 + (tid - 384));
    if (tid < 256) pfB = aload64(s1 + 128 + tid);
  }

  int cur = 0, prv = dil - 1;
  for (int t = 0; t < T_STEPS; ++t){
    const int slot = t & rmask;

    // ---- preamble: drain (prefetch loads + prior hop stores), stage to LDS ----
    asm volatile("s_waitcnt vmcnt(0)" ::: "memory");
    if (stage == 0){
      const int r = tid >> 6, c = tid & 63;
      ushort hb = f2bf(xv);
      xh_hi[r*XS + c] = hb;
      xh_lo[r*XS + c] = f2bf(xv - bf2f(hb));
    } else {
      if (tid < 384){
        const int q = (tid < 192) ? tid : tid - 192;
        ushort* plane = (tid < 192) ? xh_hi : xh_lo;
        const int r = q / 24, c4 = (q % 24) * 4;
        *(u64*)(plane + r*XS + c4) = pfA;
      } else if (stage == 3){
        *(u64*)(o1p + 4*(tid - 384)) = pfA;
      }
      if (stage == 3 && tid < 256) *(u64*)(o1p + 4*(128 + tid)) = pfB;
    }
    // h-copy: prev_h -> cols [KIN,KIN+32), del_h -> cols [KIN+32,KIN+64)
    {
      const int which = tid >> 8, rem = tid & 255, r = rem >> 5, c = rem & 31;
      const int srcslot = (which == 1 && t >= dil) ? cur : prv;
      xh_hi[r*XS + KIN + which*32 + c] = h_hi[srcslot*(NB*32) + r*32 + c];
      xh_lo[r*XS + KIN + which*32 + c] = h_lo[srcslot*(NB*32) + r*32 + c];
    }
    __syncthreads();   // B1
    if (tid == 0){
      if (stage > 0){
        astore32(my_consA, (uint)(t+1));
        if (stage == 3) astore32(my_consB, (uint)(t+1));
      }
      if (stage < 3 && t >= 1) astore32(my_prod, (uint)t);   // steps <= t-1 drained
    }
    // stage3: deferred y store (step t-1's projection, staged in yst)
    if (stage == 3 && t > 0){
      y_out[(size_t)((t-1)*BATCH + b0r + (tid>>6))*64 + (tid&63)] = yst[tid];
    }
    // early flag loads (results consumed much later -> latency hidden)
    const bool pre = (t + 1 < T_STEPS);
    uint up_f = 0, up_f1 = 0;
    if (pre && stage > 0)  up_f  = aload32(up_prod);
    if (pre && stage == 3) up_f1 = aload32(up_prod1);
    if (stage < 3 && t >= rd)  fvDA = aload32(dnA);
    if (stage == 1 && t >= rd) fvDB = aload32(dnB);

    // ---- GEMM: g = xh @ W^T + b  (pure ds_read + MFMA) ----
    f32x4 acc[4];
    #pragma unroll
    for (int j = 0; j < 4; ++j) acc[j] = (f32x4){bias[j],bias[j],bias[j],bias[j]};
    const int abase = l15*XS + hi*8;
    #pragma unroll
    for (int ks = 0; ks < 5; ++ks){
      if (ks*32 < K){
        bf16x8 ahi = *(const bf16x8*)(xh_hi + abase + ks*32);
        bf16x8 alo = *(const bf16x8*)(xh_lo + abase + ks*32);
        #pragma unroll
        for (int j = 0; j < 4; ++j){
          acc[j] = __builtin_amdgcn_mfma_f32_16x16x32_bf16(ahi, whi[j][ks], acc[j], 0, 0, 0);
          acc[j] = __builtin_amdgcn_mfma_f32_16x16x32_bf16(alo, whi[j][ks], acc[j], 0, 0, 0);
          acc[j] = __builtin_amdgcn_mfma_f32_16x16x32_bf16(ahi, wlo[j][ks], acc[j], 0, 0, 0);
        }
      }
    }

    // ---- prefetch data for t+1 (latency hidden under gates + stores) ----
    if (pre){
      if (stage == 0){
        xv = x[(size_t)((t+1)*BATCH + b0r + (tid>>6))*64 + (tid&63)];
      } else {
        const uint need = (uint)(t + 2);
        while (up_f < need){ __builtin_amdgcn_s_sleep(2); up_f = aload32(up_prod); }
        if (stage == 3)
          while (up_f1 < need){ __builtin_amdgcn_s_sleep(2); up_f1 = aload32(up_prod1); }
        const int ns = (t + 1) & rmask;
        if (stage < 3){
          if (tid < 384) pfA = aload64(hop_in + (size_t)(ns*64 + rep)*384 + tid);
        } else {
          const u64* s2 = hop2 + (size_t)(ns*64 + rep)*384;
          const u64* s1 = hop1 + (size_t)(ns*64 + rep)*384;
          pfA = (tid < 384) ? aload64(s2 + tid) : aload64(s1 + (tid - 384));
          if (tid < 256) pfB = aload64(s1 + 128 + tid);
        }
      }
    }

    // ---- gates + state update (lane owns state sidx, rows hi*4..hi*4+3) ----
    f32x4 pc = *(const f32x4*)(sh_c + prv*(128*CSTR) + sidx*CSTR + (hi&1)*4);
    f32x4 dc = *(const f32x4*)(sh_c + cur*(128*CSTR) + sidx*CSTR + (hi&1)*4);
    const bool has_prev = (t >= 1), has_del = (t >= dil);
    f32x4 ncv; float whv[4];
    #pragma unroll
    for (int k = 0; k < 4; ++k){
      float f  = sigm(acc[0][k] + 1.0f);
      float cd = tanh_fast(acc[1][k]);
      float al = sigm(acc[2][k]);
      float og = sigm(acc[3][k]);
      float wt = has_del ? (al*pc[k] + (1.0f - al)*dc[k]) : pc[k];
      float nc = has_prev ? (f*wt + (1.0f - f)*cd) : cd;
      ncv[k] = nc;
      whv[k] = og * nc;
    }
    if (hi < 2){
      *(f32x4*)(sh_c + cur*(128*CSTR) + sidx*CSTR + hi*4) = ncv;
      #pragma unroll
      for (int k = 0; k < 4; ++k){
        const int r = hi*4 + k;
        const float w = whv[k];
        if (sidx < OUTC){
          if (stage == 3){
            o3f[r*OUTC + sidx] = w;
          } else {
            ushort hb = f2bf(w);
            outp[r*OUTC + sidx]       = hb;
            outp[768 + r*OUTC + sidx] = f2bf(w - bf2f(hb));
          }
        } else {
          ushort hb = f2bf(w);
          h_hi[cur*(NB*32) + r*32 + (sidx - OUTC)] = hb;
          h_lo[cur*(NB*32) + r*32 + (sidx - OUTC)] = f2bf(w - bf2f(hb));
        }
      }
    }
    __syncthreads();   // B2

    // ---- stage output ----
    if (stage < 3){
      if (t >= rd){   // with rd >= T_STEPS this never executes
        const uint need = (uint)(t - rd + 1);
        while (fvDA < need){ __builtin_amdgcn_s_sleep(2); fvDA = aload32(dnA); }
        if (stage == 1)
          while (fvDB < need){ __builtin_amdgcn_s_sleep(2); fvDB = aload32(dnB); }
      }
      if (tid < 384){
        u64 v = *(const u64*)(outp + 4*tid);
        astore64(hop_out + (size_t)(slot*64 + rep)*384 + tid, v);   // fire & forget
      }
    } else {
      // resnet: pb = out3 + out1 -> PA planes in outp
      for (int j = tid; j < 768; j += 512){
        float v = o3f[j] + bf2f(o1p[j]) + bf2f(o1p[768 + j]);
        ushort hb = f2bf(v);
        outp[j]       = hb;
        outp[768 + j] = f2bf(v - bf2f(hb));
      }
      __syncthreads(); // B3
      if (wv < 4){
        f32x4 acc1 = (f32x4){bav, bav, bav, bav};
        const int pbase = l15*96 + hi*8;
        #pragma unroll
        for (int ks = 0; ks < 3; ++ks){
          bf16x8 ahi = *(const bf16x8*)(outp + pbase + ks*32);
          bf16x8 alo = *(const bf16x8*)(outp + 768 + pbase + ks*32);
          acc1 = __builtin_amdgcn_mfma_f32_16x16x32_bf16(ahi, phi[ks], acc1, 0, 0, 0);
          acc1 = __builtin_amdgcn_mfma_f32_16x16x32_bf16(alo, phi[ks], acc1, 0, 0, 0);
          acc1 = __builtin_amdgcn_mfma_f32_16x16x32_bf16(ahi, plo[ks], acc1, 0, 0, 0);
        }
        if (hi < 2){
          const int ocol = 16*wv + l15;
          #pragma unroll
          for (int k = 0; k < 4; ++k){
            yst[(hi*4 + k)*64 + ocol] = acc1[k];   // deferred to next step's y store
          }
        }
      }
    }
    prv = cur;
    cur = (cur + 1 == dil) ? 0 : cur + 1;
  }

  // ---- postloop: drain, final deferred y, terminal flags ----
  asm volatile("s_waitcnt vmcnt(0)" ::: "memory");
  __syncthreads();
  if (stage == 3){
    y_out[(size_t)((T_STEPS-1)*BATCH + b0r + (tid>>6))*64 + (tid&63)] = yst[tid];
  }
  if (stage < 3 && tid == 0) astore32(my_prod, (uint)(T_STEPS + 2));
}

extern "C" void kernel_launch(void* const* d_in, const int* in_sizes, int n_in,
                              void* d_out, int out_size, void* d_ws, size_t ws_size,
                              hipStream_t stream) {
  (void)in_sizes; (void)n_in; (void)out_size;
  const float* x  = (const float*)d_in[0];
  const float* W0 = (const float*)d_in[1];
  const float* b0 = (const float*)d_in[2];
  const float* W1 = (const float*)d_in[3];
  const float* b1 = (const float*)d_in[4];
  const float* W2 = (const float*)d_in[5];
  const float* b2 = (const float*)d_in[6];
  const float* W3 = (const float*)d_in[7];
  const float* b3 = (const float*)d_in[8];
  const float* Wa = (const float*)d_in[9];
  const float* ba = (const float*)d_in[10];
  float* out = (float*)d_out;

  // Ring depth: largest power of 2 (<= 512) whose rings fit in d_ws.
  // rd >= 512 => every step has a unique slot => zero downstream-full checks.
  int rd = 16;
  if (ws_size > 65536){
    size_t avail = ws_size - 65536;
    while (rd < 512 && (size_t)(rd * 2) * 64 * 9216 <= avail) rd *= 2;
  }

  // Flags: 128B line each. prod[3][64] @0, consA[3][64] @24576, consB[64] @49152.
  uint* prod  = (uint*)d_ws;
  uint* consA = (uint*)((char*)d_ws + 24576);
  uint* consB = (uint*)((char*)d_ws + 49152);
  u64* hop0 = (u64*)((char*)d_ws + 65536);   // [rd][64][384] u64 (hi/lo planes)
  u64* hop1 = hop0 + (size_t)rd*64*384;
  u64* hop2 = hop1 + (size_t)rd*64*384;

  hipMemsetAsync(d_ws, 0, 65536, stream);  // re-zero flags every call
  hipLaunchKernelGGL(rnn_pipeline, dim3(256), dim3(512), 0, stream,
                     x, W0, b0, W1, b1, W2, b2, W3, b3, Wa, ba,
                     out, prod, consA, consB, hop0, hop1, hop2, rd);
}

// Round 11
// 2095.389 us; speedup vs baseline: 1.4019x; 1.0524x over previous
//
#include <hip/hip_runtime.h>

typedef unsigned int uint;
typedef unsigned short ushort;
typedef unsigned long long u64;
typedef __attribute__((ext_vector_type(8))) short bf16x8;
typedef __attribute__((ext_vector_type(4))) float f32x4;

// Problem constants
#define T_STEPS 512
#define BATCH   512
#define NB      8        // batch rows per replica
#define XS      104      // xi plane row stride (ushort) - input cols only
#define HS      40       // h ring row stride (ushort)
#define HSLOT   (16*HS)  // h ring slot stride (16 rows, rows 8-15 stay zero)
#define CSTR    12       // c-ring pad: floats per (slot,sidx) row
#define OUTC    96
#define FSTR    32       // flag stride in uints (128B line per flag)
#define NITER   256      // 2 steps per iteration

__device__ __forceinline__ ushort f2bf(float f){
  uint u = __builtin_bit_cast(uint, f);
  u = (u + 0x7FFFu + ((u >> 16) & 1u)) >> 16;   // RNE
  return (ushort)u;
}
__device__ __forceinline__ float bf2f(ushort h){
  uint u = ((uint)h) << 16; return __builtin_bit_cast(float, u);
}
__device__ __forceinline__ float sigm(float x){
  float e = __builtin_exp2f(-1.44269504f * x);
  return __builtin_amdgcn_rcpf(1.0f + e);
}
__device__ __forceinline__ float tanh_fast(float x){
  float e = __builtin_exp2f(-2.88539008f * x);
  return 2.0f * __builtin_amdgcn_rcpf(1.0f + e) - 1.0f;
}
// Relaxed agent-scope atomics: LLC-coherent, no L1/L2 invalidate/writeback.
__device__ __forceinline__ uint aload32(const uint* p){
  return __hip_atomic_load(p, __ATOMIC_RELAXED, __HIP_MEMORY_SCOPE_AGENT);
}
__device__ __forceinline__ void astore32(uint* p, uint v){
  __hip_atomic_store(p, v, __ATOMIC_RELAXED, __HIP_MEMORY_SCOPE_AGENT);
}
__device__ __forceinline__ u64 aload64(const u64* p){
  return __hip_atomic_load(p, __ATOMIC_RELAXED, __HIP_MEMORY_SCOPE_AGENT);
}
__device__ __forceinline__ void astore64(u64* p, u64 v){
  __hip_atomic_store(p, v, __ATOMIC_RELAXED, __HIP_MEMORY_SCOPE_AGENT);
}

// 4-stage pipeline (stage = blockIdx.x>>6, rep = blockIdx.x&63), NB=8 rows.
// TWO time-steps fused per iteration: staging/flags/prefetch/stores amortized.
// GEMM reads prev_h/del_h fragments DIRECTLY from the LDS h-ring (no h-copy);
// xi buffers hold input columns only. pc comes from the previous step's ncv
// registers (lane-private). Producer flags lag-2 (in-order vmcnt proof, no
// manual vmcnt in loop). Optimistic flag checks, blocking fallback.
__global__ __launch_bounds__(512, 1)
void rnn_pipeline(const float* __restrict__ x,
                  const float* __restrict__ W0, const float* __restrict__ b0,
                  const float* __restrict__ W1, const float* __restrict__ b1,
                  const float* __restrict__ W2, const float* __restrict__ b2,
                  const float* __restrict__ W3, const float* __restrict__ b3,
                  const float* __restrict__ Wa, const float* __restrict__ ba,
                  float* __restrict__ y_out,
                  uint* __restrict__ prod, uint* __restrict__ consA,
                  uint* __restrict__ consB,
                  u64* __restrict__ hop0, u64* __restrict__ hop1,
                  u64* __restrict__ hop2, int rd)
{
  const int tid  = threadIdx.x;
  const int wv   = tid >> 6;      // wave 0..7
  const int lane = tid & 63;
  const int l15  = lane & 15;
  const int hi   = lane >> 4;     // 0..3
  const int rep  = blockIdx.x & 63;
  const int stage= blockIdx.x >> 6;
  const int b0r  = rep * NB;
  const int rmask= rd - 1;

  const int dil = (stage==0)?1:(stage==1)?3:(stage==2)?6:12;
  const int KIN = (stage==0)?64:96;
  const int K   = KIN + 64;
  const float* Wl = (stage==0)?W0:(stage==1)?W1:(stage==2)?W2:W3;
  const float* bl = (stage==0)?b0:(stage==1)?b1:(stage==2)?b2:b3;

  __shared__ __align__(16) ushort xiA_hi[16*XS], xiA_lo[16*XS];  // step t input
  __shared__ __align__(16) ushort xiB_hi[16*XS], xiB_lo[16*XS];  // step u input
  __shared__ __align__(16) float  sh_c[12*128*CSTR];             // c ring
  __shared__ __align__(16) ushort h_hi[12*HSLOT], h_lo[12*HSLOT];// h ring (16 rows)
  __shared__ __align__(16) ushort outpA[2304], outpB[2304];      // hop payloads
  __shared__ __align__(16) ushort o1pA[1536], o1pB[1536];        // stage3 out1
  __shared__ __align__(16) float  o3fA[768],  o3fB[768];         // stage3 out3

  for (int i = tid; i < 16*XS; i += 512){ xiA_hi[i]=0; xiA_lo[i]=0; xiB_hi[i]=0; xiB_lo[i]=0; }
  for (int i = tid; i < 12*128*CSTR; i += 512) sh_c[i] = 0.0f;
  for (int i = tid; i < 12*HSLOT; i += 512){ h_hi[i]=0; h_lo[i]=0; }
  for (int i = tid; i < 2304; i += 512){ outpA[i]=0; outpB[i]=0; }
  for (int i = tid; i < 1536; i += 512){ o1pA[i]=0; o1pB[i]=0; }
  for (int i = tid; i < 768; i += 512){ o3fA[i]=0.0f; o3fB[i]=0.0f; }

  const int sidx = 16*wv + l15;  // state index 0..127 owned by this lane

  // Layer weights as split-bf16 MFMA B-fragments (zero-padded past K).
  bf16x8 whi[4][5], wlo[4][5];
  #pragma unroll
  for (int j = 0; j < 4; ++j){
    const int grow = 128*j + sidx;
    #pragma unroll
    for (int ks = 0; ks < 5; ++ks){
      bf16x8 vh, vl;
      const int cb = ks*32 + hi*8;
      if (cb < K){
        const float* p = Wl + (size_t)grow*K + cb;
        #pragma unroll
        for (int q = 0; q < 8; ++q){
          float w = p[q];
          ushort h = f2bf(w);
          vh[q] = (short)h;
          vl[q] = (short)f2bf(w - bf2f(h));
        }
      } else {
        #pragma unroll
        for (int q = 0; q < 8; ++q){ vh[q] = 0; vl[q] = 0; }
      }
      whi[j][ks] = vh; wlo[j][ks] = vl;
    }
  }
  float bias[4];
  #pragma unroll
  for (int j = 0; j < 4; ++j) bias[j] = bl[128*j + sidx];

  // Projection weights (stage3, waves 0..3)
  bf16x8 phi[3], plo[3];
  #pragma unroll
  for (int ks = 0; ks < 3; ++ks){
    bf16x8 z;
    #pragma unroll
    for (int q = 0; q < 8; ++q) z[q]=0;
    phi[ks]=z; plo[ks]=z;
  }
  float bav = 0.0f;
  if (stage == 3 && wv < 4){
    const int ocol = 16*wv + l15;
    #pragma unroll
    for (int ks = 0; ks < 3; ++ks){
      const float* p = Wa + (size_t)ocol*96 + ks*32 + hi*8;
      bf16x8 vh, vl;
      #pragma unroll
      for (int q = 0; q < 8; ++q){
        float w = p[q];
        ushort h = f2bf(w);
        vh[q] = (short)h;
        vl[q] = (short)f2bf(w - bf2f(h));
      }
      phi[ks] = vh; plo[ks] = vl;
    }
    bav = ba[ocol];
  }

  // Flag wiring (each flag on its own 128B line)
  uint* up_prod  = (stage==1)? &prod[rep*FSTR] : (stage==2)? &prod[(64+rep)*FSTR] :
                   (stage==3)? &prod[(128+rep)*FSTR] : nullptr;
  uint* up_prod1 = (stage==3)? &prod[(64+rep)*FSTR] : nullptr;
  uint* my_prod  = (stage==0)? &prod[rep*FSTR] : (stage==1)? &prod[(64+rep)*FSTR] :
                   (stage==2)? &prod[(128+rep)*FSTR] : nullptr;
  uint* my_consA = (stage==1)? &consA[rep*FSTR] : (stage==2)? &consA[(64+rep)*FSTR] :
                   (stage==3)? &consA[(128+rep)*FSTR] : nullptr;
  uint* my_consB = (stage==3)? &consB[rep*FSTR] : nullptr;
  uint* dnA      = (stage==0)? &consA[rep*FSTR] : (stage==1)? &consA[(64+rep)*FSTR] :
                   (stage==2)? &consA[(128+rep)*FSTR] : nullptr;
  uint* dnB      = (stage==1)? &consB[rep*FSTR] : nullptr;
  const u64* hop_in  = (stage==1)? hop0 : (stage==2)? hop1 : nullptr;
  u64*       hop_out = (stage==0)? hop0 : (stage==1)? hop1 : (stage==2)? hop2 : nullptr;

  // GEMM: input-ks from xi planes, h-ks direct from h-ring slots.
  const int ax = l15*XS + hi*8;
  const int ah = l15*HS + hi*8;
  auto gemm = [&](const ushort* xhi, const ushort* xlo, int pslot, int dslot,
                  f32x4 acc[4]){
    #pragma unroll
    for (int ks = 0; ks < 5; ++ks){
      if (ks*32 < K){
        const ushort *ph, *pl; int off;
        if (ks*32 < KIN){ ph = xhi; pl = xlo; off = ax + ks*32; }
        else if (ks*32 == KIN){ ph = h_hi; pl = h_lo; off = pslot*HSLOT + ah; }
        else { ph = h_hi; pl = h_lo; off = dslot*HSLOT + ah; }
        bf16x8 a_hi = *(const bf16x8*)(ph + off);
        bf16x8 a_lo = *(const bf16x8*)(pl + off);
        #pragma unroll
        for (int j = 0; j < 4; ++j){
          acc[j] = __builtin_amdgcn_mfma_f32_16x16x32_bf16(a_hi, whi[j][ks], acc[j], 0, 0, 0);
          acc[j] = __builtin_amdgcn_mfma_f32_16x16x32_bf16(a_lo, whi[j][ks], acc[j], 0, 0, 0);
          acc[j] = __builtin_amdgcn_mfma_f32_16x16x32_bf16(a_hi, wlo[j][ks], acc[j], 0, 0, 0);
        }
      }
    }
  };
  // gates: pc from regs; dc from c-ring (or pc when dil==1). Writes c, out, h.
  auto gates = [&](const f32x4 acc[4], f32x4 pc, int cslot, bool has_prev,
                   bool has_del, ushort* outp, float* o3, f32x4& ncv_out){
    f32x4 dc;
    if (dil == 1) dc = pc;
    else dc = *(const f32x4*)(sh_c + cslot*(128*CSTR) + sidx*CSTR + (hi&1)*4);
    float whv[4];
    #pragma unroll
    for (int k = 0; k < 4; ++k){
      float f  = sigm(acc[0][k] + 1.0f);
      float cd = tanh_fast(acc[1][k]);
      float al = sigm(acc[2][k]);
      float og = sigm(acc[3][k]);
      float wt = has_del ? (al*pc[k] + (1.0f - al)*dc[k]) : pc[k];
      float nc = has_prev ? (f*wt + (1.0f - f)*cd) : cd;
      ncv_out[k] = nc;
      whv[k] = og * nc;
    }
    if (hi < 2){
      *(f32x4*)(sh_c + cslot*(128*CSTR) + sidx*CSTR + hi*4) = ncv_out;
      #pragma unroll
      for (int k = 0; k < 4; ++k){
        const int r = hi*4 + k;
        const float w = whv[k];
        if (sidx < OUTC){
          if (stage == 3){
            o3[r*OUTC + sidx] = w;
          } else {
            ushort hb = f2bf(w);
            outp[r*OUTC + sidx]       = hb;
            outp[768 + r*OUTC + sidx] = f2bf(w - bf2f(hb));
          }
        } else {
          ushort hb = f2bf(w);
          h_hi[cslot*HSLOT + r*HS + (sidx - OUTC)] = hb;
          h_lo[cslot*HSLOT + r*HS + (sidx - OUTC)] = f2bf(w - bf2f(hb));
        }
      }
    }
  };
  auto proj = [&](const ushort* outp, int s){
    if (wv < 4){
      f32x4 a1 = (f32x4){bav, bav, bav, bav};
      const int pbase = l15*96 + hi*8;
      #pragma unroll
      for (int ks = 0; ks < 3; ++ks){
        bf16x8 a_hi = *(const bf16x8*)(outp + pbase + ks*32);
        bf16x8 a_lo = *(const bf16x8*)(outp + 768 + pbase + ks*32);
        a1 = __builtin_amdgcn_mfma_f32_16x16x32_bf16(a_hi, phi[ks], a1, 0, 0, 0);
        a1 = __builtin_amdgcn_mfma_f32_16x16x32_bf16(a_lo, phi[ks], a1, 0, 0, 0);
        a1 = __builtin_amdgcn_mfma_f32_16x16x32_bf16(a_hi, plo[ks], a1, 0, 0, 0);
      }
      if (hi < 2){
        const int ocol = 16*wv + l15;
        #pragma unroll
        for (int k = 0; k < 4; ++k)
          y_out[(size_t)(s*BATCH + b0r + hi*4 + k)*64 + ocol] = a1[k];
      }
    }
  };

  __syncthreads();

  // ---- preloop: block until producer >= 4, load iteration-0 data ----
  u64 pfA_t = 0, pfA_u = 0, pfC_t = 0, pfC_u = 0;
  float xv_t = 0.0f, xv_u = 0.0f;
  uint fvU = 0, fvU1 = 0, fvDA = 0, fvDB = 0;
  if (stage == 0){
    xv_t = x[(size_t)(b0r + (tid>>6))*64 + (tid&63)];
    xv_u = x[(size_t)(BATCH + b0r + (tid>>6))*64 + (tid&63)];
  } else if (stage < 3){
    do { fvU = aload32(up_prod); if (fvU < 4u) __builtin_amdgcn_s_sleep(2); } while (fvU < 4u);
    if (tid < 384){
      pfA_t = aload64(hop_in + (size_t)rep*384 + tid);
      pfA_u = aload64(hop_in + (size_t)(64 + rep)*384 + tid);
    }
  } else {
    do { fvU  = aload32(up_prod);  if (fvU  < 4u) __builtin_amdgcn_s_sleep(2); } while (fvU  < 4u);
    do { fvU1 = aload32(up_prod1); if (fvU1 < 4u) __builtin_amdgcn_s_sleep(2); } while (fvU1 < 4u);
    if (tid < 384){
      pfA_t = aload64(hop2 + (size_t)rep*384 + tid);
      pfA_u = aload64(hop2 + (size_t)(64 + rep)*384 + tid);
      pfC_t = aload64(hop1 + (size_t)rep*384 + tid);
      pfC_u = aload64(hop1 + (size_t)(64 + rep)*384 + tid);
    }
  }

  f32x4 ncv_prev = (f32x4){0.0f, 0.0f, 0.0f, 0.0f};
  int cur_t = 0, prv_t = dil - 1;

  for (int it = 0; it < NITER; ++it){
    const int t = 2*it, u = t + 1;
    const int slot_t = t & rmask, slot_u = u & rmask;
    const int cur_u = (cur_t + 1 == dil) ? 0 : cur_t + 1;
    const int del_t = (t >= dil) ? cur_t : prv_t;
    const int del_u = (u >= dil) ? cur_u : cur_t;

    // ---- upstream optimistic check (sample is 1 iteration old) ----
    if (stage > 0){
      const bool bad = (fvU < (uint)(t+4)) || (stage == 3 && fvU1 < (uint)(t+4));
      if (bad){
        if (lane == 0){
          while (aload32(up_prod) < (uint)(t+2)) __builtin_amdgcn_s_sleep(2);
          if (stage == 3)
            while (aload32(up_prod1) < (uint)(t+2)) __builtin_amdgcn_s_sleep(2);
        }
        if (tid < 384){
          if (stage < 3){
            pfA_t = aload64(hop_in + (size_t)(slot_t*64 + rep)*384 + tid);
            pfA_u = aload64(hop_in + (size_t)(slot_u*64 + rep)*384 + tid);
          } else {
            pfA_t = aload64(hop2 + (size_t)(slot_t*64 + rep)*384 + tid);
            pfA_u = aload64(hop2 + (size_t)(slot_u*64 + rep)*384 + tid);
            pfC_t = aload64(hop1 + (size_t)(slot_t*64 + rep)*384 + tid);
            pfC_u = aload64(hop1 + (size_t)(slot_u*64 + rep)*384 + tid);
          }
        }
      }
    }
    // ---- stage both steps' inputs (compiler waits exactly the pf regs) ----
    if (stage == 0){
      const int r = tid >> 6, c = tid & 63;
      ushort hb = f2bf(xv_t);
      xiA_hi[r*XS + c] = hb; xiA_lo[r*XS + c] = f2bf(xv_t - bf2f(hb));
      hb = f2bf(xv_u);
      xiB_hi[r*XS + c] = hb; xiB_lo[r*XS + c] = f2bf(xv_u - bf2f(hb));
    } else {
      if (tid < 384){
        const int q = (tid < 192) ? tid : tid - 192;
        const int off = (q/24)*XS + (q%24)*4;
        ushort* plA = (tid < 192) ? xiA_hi : xiA_lo;
        ushort* plB = (tid < 192) ? xiB_hi : xiB_lo;
        *(u64*)(plA + off) = pfA_t;
        *(u64*)(plB + off) = pfA_u;
        if (stage == 3){
          *(u64*)(o1pA + 4*tid) = pfC_t;
          *(u64*)(o1pB + 4*tid) = pfC_u;
        }
      }
    }
    __syncthreads();   // B1
    if (tid == 0){
      if (stage > 0){
        astore32(my_consA, (uint)(t+2));
        if (stage == 3) astore32(my_consB, (uint)(t+2));
      }
      if (stage < 3 && it >= 2) astore32(my_prod, (uint)(t-2));  // lag-2 proof
    }
    // ---- downstream-full check (optimistic; blocking fallback) ----
    if (stage < 3 && u >= rd){
      const bool badc = (fvDA < (uint)(t+4-rd)) || (stage == 1 && fvDB < (uint)(t+4-rd));
      if (badc && lane == 0){
        while (aload32(dnA) < (uint)(t+2-rd)) __builtin_amdgcn_s_sleep(2);
        if (stage == 1)
          while (aload32(dnB) < (uint)(t+2-rd)) __builtin_amdgcn_s_sleep(2);
      }
    }
    // ---- issue prefetch for next iteration (window = full iteration) ----
    if (it + 1 < NITER){
      const int nt = (t+2) & rmask, nu = (t+3) & rmask;
      if (stage == 0){
        xv_t = x[(size_t)((t+2)*BATCH + b0r + (tid>>6))*64 + (tid&63)];
        xv_u = x[(size_t)((t+3)*BATCH + b0r + (tid>>6))*64 + (tid&63)];
      } else if (stage < 3){
        if (tid < 384){
          pfA_t = aload64(hop_in + (size_t)(nt*64 + rep)*384 + tid);
          pfA_u = aload64(hop_in + (size_t)(nu*64 + rep)*384 + tid);
        }
        fvU = aload32(up_prod);
      } else {
        if (tid < 384){
          pfA_t = aload64(hop2 + (size_t)(nt*64 + rep)*384 + tid);
          pfA_u = aload64(hop2 + (size_t)(nu*64 + rep)*384 + tid);
          pfC_t = aload64(hop1 + (size_t)(nt*64 + rep)*384 + tid);
          pfC_u = aload64(hop1 + (size_t)(nu*64 + rep)*384 + tid);
        }
        fvU  = aload32(up_prod);
        fvU1 = aload32(up_prod1);
      }
    }
    if (stage < 3) fvDA = aload32(dnA);
    if (stage == 1) fvDB = aload32(dnB);
    asm volatile("" ::: "memory");

    // ---- STEP t ----
    f32x4 acc[4];
    #pragma unroll
    for (int j = 0; j < 4; ++j) acc[j] = (f32x4){bias[j],bias[j],bias[j],bias[j]};
    gemm(xiA_hi, xiA_lo, prv_t, del_t, acc);
    f32x4 ncv;
    gates(acc, ncv_prev, cur_t, (t >= 1), (t >= dil), outpA, o3fA, ncv);
    ncv_prev = ncv;
    __syncthreads();   // Bmid: h(cur_t), outpA/o3fA visible

    if (stage == 3){
      // resnet(t): outpA = o3fA + o1pA (reads post-Bmid; PROJ reads after B2)
      for (int j = tid; j < 768; j += 512){
        float v = o3fA[j] + bf2f(o1pA[j]) + bf2f(o1pA[768 + j]);
        ushort hb = f2bf(v);
        outpA[j]       = hb;
        outpA[768 + j] = f2bf(v - bf2f(hb));
      }
    }
    // ---- STEP u ----
    #pragma unroll
    for (int j = 0; j < 4; ++j) acc[j] = (f32x4){bias[j],bias[j],bias[j],bias[j]};
    gemm(xiB_hi, xiB_lo, cur_t, del_u, acc);
    gates(acc, ncv_prev, cur_u, true, (u >= dil), outpB, o3fB, ncv);
    ncv_prev = ncv;
    __syncthreads();   // B2

    if (stage < 3){
      if (tid < 384){
        astore64(hop_out + (size_t)(slot_t*64 + rep)*384 + tid, *(const u64*)(outpA + 4*tid));
        astore64(hop_out + (size_t)(slot_u*64 + rep)*384 + tid, *(const u64*)(outpB + 4*tid));
      }
    } else {
      proj(outpA, t);   // outpA stable after B2
      for (int j = tid; j < 768; j += 512){
        float v = o3fB[j] + bf2f(o1pB[j]) + bf2f(o1pB[768 + j]);
        ushort hb = f2bf(v);
        outpB[j]       = hb;
        outpB[768 + j] = f2bf(v - bf2f(hb));
      }
      __syncthreads(); // B3u
      proj(outpB, u);
    }
    prv_t = cur_u;
    cur_t = (cur_u + 1 == dil) ? 0 : cur_u + 1;
  }

  // ---- postloop: drain all stores, terminal flags ----
  asm volatile("s_waitcnt vmcnt(0)" ::: "memory");
  __syncthreads();
  if (stage < 3 && tid == 0) astore32(my_prod, (uint)(T_STEPS + 8));
}

extern "C" void kernel_launch(void* const* d_in, const int* in_sizes, int n_in,
                              void* d_out, int out_size, void* d_ws, size_t ws_size,
                              hipStream_t stream) {
  (void)in_sizes; (void)n_in; (void)out_size;
  const float* x  = (const float*)d_in[0];
  const float* W0 = (const float*)d_in[1];
  const float* b0 = (const float*)d_in[2];
  const float* W1 = (const float*)d_in[3];
  const float* b1 = (const float*)d_in[4];
  const float* W2 = (const float*)d_in[5];
  const float* b2 = (const float*)d_in[6];
  const float* W3 = (const float*)d_in[7];
  const float* b3 = (const float*)d_in[8];
  const float* Wa = (const float*)d_in[9];
  const float* ba = (const float*)d_in[10];
  float* out = (float*)d_out;

  // Ring depth: largest power of 2 (<= 512) whose rings fit in d_ws.
  int rd = 16;
  if (ws_size > 65536){
    size_t avail = ws_size - 65536;
    while (rd < 512 && (size_t)(rd * 2) * 64 * 9216 <= avail) rd *= 2;
  }

  // Flags: 128B line each. prod[3][64] @0, consA[3][64] @24576, consB[64] @49152.
  uint* prod  = (uint*)d_ws;
  uint* consA = (uint*)((char*)d_ws + 24576);
  uint* consB = (uint*)((char*)d_ws + 49152);
  u64* hop0 = (u64*)((char*)d_ws + 65536);   // [rd][64][384] u64 (hi/lo planes)
  u64* hop1 = hop0 + (size_t)rd*64*384;
  u64* hop2 = hop1 + (size_t)rd*64*384;

  hipMemsetAsync(d_ws, 0, 65536, stream);  // re-zero flags every call
  hipLaunchKernelGGL(rnn_pipeline, dim3(256), dim3(512), 0, stream,
                     x, W0, b0, W1, b1, W2, b2, W3, b3, Wa, ba,
                     out, prod, consA, consB, hop0, hop1, hop2, rd);
}